// Round 6
// baseline (57.904 us; speedup 1.0000x reference)
//
#include <hip/hip_runtime.h>

#define H 1024
#define W 1024
#define TX 32
#define TY 64
#define LR 72    // TY+8 luma rows
#define LCP 44   // padded luma row stride (11 quads, odd) ; cols 0..39 used
#define SCP 44   // padded sum row stride  (11 quads, odd) ; cols 0..35 used
#define VR 68    // TY+4 vw rows
#define VCP 37   // padded vw row stride in float4 (odd quads); cols 0..35 used

__global__ __launch_bounds__(256)
void kuwahara_kernel(const float* __restrict__ inp, float* __restrict__ out) {
    __shared__ float  s_lum[LR][LCP];    // zero-padded luma           (12.4 KB)
    __shared__ float  s_s  [LR][SCP];    // horizontal 5-sum of luma   (12.4 KB)
    __shared__ float  s_sq [LR][SCP];    // horizontal 5-sum of luma^2 (12.4 KB)
    __shared__ float4 s_vw [VR][VCP];    // (r,g,b,k->weight), edge-rep (39.3 KB)

    const int tid = threadIdx.x;
    const int n  = blockIdx.z;
    const int y0 = blockIdx.y * TY;
    const int x0 = blockIdx.x * TX;

    const float* __restrict__ pR = inp + ((size_t)(4*n + 0) << 20);
    const float* __restrict__ pG = inp + ((size_t)(4*n + 1) << 20);
    const float* __restrict__ pB = inp + ((size_t)(4*n + 2) << 20);
    const float* __restrict__ pK = inp + ((size_t)(4*n + 3) << 20);

    const int tx  = tid & 31;   // column within tile
    const int tg  = tid >> 5;   // row-group: owns rows 8*tg .. 8*tg+7
    const int gx  = x0 + tx;
    const int pr0 = tg << 3;

    // ---- k at this thread's 8 output pixels (only long-lived state) ----
    float kc[8];
#pragma unroll
    for (int p = 0; p < 8; ++p)
        kc[p] = pK[((y0 + pr0 + p) << 10) + gx];

    // ---- stage 1: float4-vectorized halo load ----
    // 720 tasks: j in [0,72), q in [0,10); each handles 4 consecutive pixels.
    for (int idx = tid; idx < LR * 10; idx += 256) {
        int j  = idx / 10, q = idx - j * 10;
        int gy = y0 - 4 + j;
        int cy = min(max(gy, 0), H - 1);
        int gcs = x0 - 4 + (q << 2);
        const int base = cy << 10;
        bool vwrow = (j >= 2) && (j < LR - 2);
        float rr[4], gg[4], bb[4], kk[4];
        if (gcs >= 0 && gcs <= W - 4) {          // x-interior: vector loads
            float4 r4 = *(const float4*)(pR + base + gcs);
            float4 g4 = *(const float4*)(pG + base + gcs);
            float4 b4 = *(const float4*)(pB + base + gcs);
            rr[0]=r4.x; rr[1]=r4.y; rr[2]=r4.z; rr[3]=r4.w;
            gg[0]=g4.x; gg[1]=g4.y; gg[2]=g4.z; gg[3]=g4.w;
            bb[0]=b4.x; bb[1]=b4.y; bb[2]=b4.z; bb[3]=b4.w;
            if (vwrow) {
                float4 k4 = *(const float4*)(pK + base + gcs);
                kk[0]=k4.x; kk[1]=k4.y; kk[2]=k4.z; kk[3]=k4.w;
            }
        } else {                                  // x-border: clamped scalar
#pragma unroll
            for (int e = 0; e < 4; ++e) {
                int cx = min(max(gcs + e, 0), W - 1);
                rr[e] = pR[base + cx]; gg[e] = pG[base + cx];
                bb[e] = pB[base + cx];
                kk[e] = vwrow ? pK[base + cx] : 0.f;
            }
        }
        bool rowIn = ((unsigned)gy < (unsigned)H);
        float lv[4];
#pragma unroll
        for (int e = 0; e < 4; ++e) {
            bool colIn = ((unsigned)(gcs + e) < (unsigned)W);
            lv[e] = (rowIn && colIn)
                      ? fmaf(0.2126f, rr[e], fmaf(0.7152f, gg[e], 0.0722f * bb[e]))
                      : 0.0f;                    // zero pad (box filter), row AND col
        }
        *(float4*)&s_lum[j][q << 2] = make_float4(lv[0], lv[1], lv[2], lv[3]);
        if (vwrow) {
#pragma unroll
            for (int e = 0; e < 4; ++e) {
                int iv = (q << 2) + e - 2;
                if (iv >= 0 && iv < VR - 32 + 0 + 36 - 36 + 36)  // iv < 36
                    if (iv < 36)
                        s_vw[j - 2][iv] = make_float4(rr[e], gg[e], bb[e], kk[e]);
            }
        }
    }
    __syncthreads();

    // ---- stage 2: horizontal sliding 5-sums, 4 outputs per task ----
    // 648 tasks: j in [0,72), q in [0,9)
    for (int idx = tid; idx < LR * 9; idx += 256) {
        int j = idx / 9, q = idx - j * 9;
        int c = q << 2;
        float4 v0 = *(const float4*)&s_lum[j][c];
        float4 v1 = *(const float4*)&s_lum[j][c + 4];
        float l[8] = {v0.x, v0.y, v0.z, v0.w, v1.x, v1.y, v1.z, v1.w};
        float s0 = ((l[0] + l[1]) + (l[2] + l[3])) + l[4];
        float s1 = s0 - l[0] + l[5];
        float s2 = s1 - l[1] + l[6];
        float s3 = s2 - l[2] + l[7];
        float m[8];
#pragma unroll
        for (int e = 0; e < 8; ++e) m[e] = l[e] * l[e];
        float u0 = ((m[0] + m[1]) + (m[2] + m[3])) + m[4];
        float u1 = u0 - m[0] + m[5];
        float u2 = u1 - m[1] + m[6];
        float u3 = u2 - m[2] + m[7];
        *(float4*)&s_s [j][c] = make_float4(s0, s1, s2, s3);
        *(float4*)&s_sq[j][c] = make_float4(u0, u1, u2, u3);
    }
    __syncthreads();

    // ---- stage 3: vertical 5-sum at clamped center -> variance -> weight ----
    // 612 tasks: j2 in [0,68), q in [0,9)
    for (int idx = tid; idx < VR * 9; idx += 256) {
        int j2 = idx / 9, q = idx - j2 * 9;
        int c  = q << 2;
        int gyc = min(max(y0 - 2 + j2, 0), H - 1);  // clamped window center row
        int js  = gyc - y0 + 2;
        int g0  = x0 - 2 + c;                       // unclamped center col of e=0
        float as[4], aq[4];
        if (g0 >= 0 && g0 + 3 <= W - 1) {           // cols interior: vector path
            float4 accs = make_float4(0.f, 0.f, 0.f, 0.f);
            float4 accq = make_float4(0.f, 0.f, 0.f, 0.f);
#pragma unroll
            for (int r = 0; r < 5; ++r) {
                float4 vs = *(const float4*)&s_s [js + r][c];
                float4 vq = *(const float4*)&s_sq[js + r][c];
                accs.x += vs.x; accs.y += vs.y; accs.z += vs.z; accs.w += vs.w;
                accq.x += vq.x; accq.y += vq.y; accq.z += vq.z; accq.w += vq.w;
            }
            as[0]=accs.x; as[1]=accs.y; as[2]=accs.z; as[3]=accs.w;
            aq[0]=accq.x; aq[1]=accq.y; aq[2]=accq.z; aq[3]=accq.w;
        } else {                                    // x-border: clamped scalar
#pragma unroll
            for (int e = 0; e < 4; ++e) {
                int is = min(max(g0 + e, 0), W - 1) - x0 + 2;
                float ss = 0.f, sq = 0.f;
#pragma unroll
                for (int r = 0; r < 5; ++r) { ss += s_s[js + r][is]; sq += s_sq[js + r][is]; }
                as[e] = ss; aq[e] = sq;
            }
        }
#pragma unroll
        for (int e = 0; e < 4; ++e) {
            float mean = as[e] * 0.04f;
            float msq  = aq[e] * 0.04f;
            float var  = fabsf(msq - mean * mean);
            float kv   = s_vw[j2][c + e].w;          // k stashed in stage 1
            s_vw[j2][c + e].w = __expf(-var * 64.0f * kv);
        }
    }
    __syncthreads();

    // ---- spatial-falloff constants (computed late to shorten live ranges) ----
    float t1[8], t4[8];
#pragma unroll
    for (int p = 0; p < 8; ++p) {
        float t = __expf(-2.56f * (1.0f - kc[p]));   // t^(dx^2+dy^2) base
        t1[p] = t;
        t4[p] = (t * t) * (t * t);
    }

    // ---- stage 4: 25-tap filter; factorized row sums shared across 8 px ----
    float accR[8], accG[8], accB[8], accW[8];
#pragma unroll
    for (int p = 0; p < 8; ++p) { accR[p] = accG[p] = accB[p] = accW[p] = 0.f; }

#pragma unroll
    for (int r = 0; r < 12; ++r) {
        const float4* row = &s_vw[pr0 + r][tx];      // single base, imm offsets
        float4 a0 = row[0], a1 = row[1], a2 = row[2], a3 = row[3], a4 = row[4];
        // partial sums by |dx|: S0 (dx=0), S1 (|dx|=1), S2 (|dx|=2)
        float S0w = a2.w;
        float S0x = a2.w * a2.x, S0y = a2.w * a2.y, S0z = a2.w * a2.z;
        float S1w = a1.w + a3.w;
        float S1x = a1.w * a1.x + a3.w * a3.x;
        float S1y = a1.w * a1.y + a3.w * a3.y;
        float S1z = a1.w * a1.z + a3.w * a3.z;
        float S2w = a0.w + a4.w;
        float S2x = a0.w * a0.x + a4.w * a4.x;
        float S2y = a0.w * a0.y + a4.w * a4.y;
        float S2z = a0.w * a0.z + a4.w * a4.z;
#pragma unroll
        for (int p = 0; p < 8; ++p) {
            const int dy = r - 2 - p;                // compile-time after unroll
            if (dy < -2 || dy > 2) continue;
            const int ady = dy < 0 ? -dy : dy;
            float rw = S0w + t1[p] * S1w + t4[p] * S2w;
            float rx = S0x + t1[p] * S1x + t4[p] * S2x;
            float ry = S0y + t1[p] * S1y + t4[p] * S2y;
            float rz = S0z + t1[p] * S1z + t4[p] * S2z;
            if (ady == 0) {
                accR[p] += rx; accG[p] += ry; accB[p] += rz; accW[p] += rw;
            } else {
                float rf = (ady == 1) ? t1[p] : t4[p];
                accR[p] += rf * rx; accG[p] += rf * ry;
                accB[p] += rf * rz; accW[p] += rf * rw;
            }
        }
    }

    float* __restrict__ oR = out + ((size_t)(3*n + 0) << 20);
    float* __restrict__ oG = out + ((size_t)(3*n + 1) << 20);
    float* __restrict__ oB = out + ((size_t)(3*n + 2) << 20);
#pragma unroll
    for (int p = 0; p < 8; ++p) {
        float4 cen = s_vw[pr0 + p + 2][tx + 2];      // center rgb (w = weight, unused)
        float cb = 16.0f + kc[p] * (0.001f - 16.0f); // center boost
        accR[p] += cb * cen.x;
        accG[p] += cb * cen.y;
        accB[p] += cb * cen.z;
        accW[p] += cb;
        float inv = __builtin_amdgcn_rcpf(accW[p]);
        int off = ((y0 + pr0 + p) << 10) + gx;
        oR[off] = cen.x + kc[p] * (accR[p] * inv - cen.x);
        oG[off] = cen.y + kc[p] * (accG[p] * inv - cen.y);
        oB[off] = cen.z + kc[p] * (accB[p] * inv - cen.z);
    }
}

extern "C" void kernel_launch(void* const* d_in, const int* in_sizes, int n_in,
                              void* d_out, int out_size, void* d_ws, size_t ws_size,
                              hipStream_t stream) {
    const float* inp = (const float*)d_in[0];
    float* out = (float*)d_out;
    dim3 grid(W / TX, H / TY, 4);
    hipLaunchKernelGGL(kuwahara_kernel, grid, dim3(256), 0, stream, inp, out);
}